// Round 1
// baseline (803.697 us; speedup 1.0000x reference)
//
#include <hip/hip_runtime.h>
#include <math.h>

#define KCLS  50000
#define KP    50048   // KCLS padded to multiple of 128 for the GEMM class dim
#define DIM   128
#define BATCH 1024
#define MAXD  16

// ---------------------------------------------------------------------------
// Kernel 1: added_weights[k] = weights[k] + sum_{p<path_len[k]} weights[path_idx[k,p]]
// One block per class, 128 threads = one thread per feature column.
__global__ __launch_bounds__(128) void aw_kernel(
    const float* __restrict__ weights, const int* __restrict__ path_idx,
    const int* __restrict__ path_len, float* __restrict__ aw)
{
    int k = blockIdx.x;
    int d = threadIdx.x;
    int len = path_len[k];
    const int* pp = path_idx + (size_t)k * MAXD;
    float acc = weights[(size_t)k * DIM + d];
    for (int p = 0; p < len; ++p) {
        acc += weights[(size_t)pp[p] * DIM + d];
    }
    aw[(size_t)k * DIM + d] = acc;
}

// ---------------------------------------------------------------------------
// Tiled transpose: src[R][128] -> dst[128][RP], zero-filling rows >= R.
// 64x64 tiles, LDS padded to 65 to avoid bank conflicts.
__global__ __launch_bounds__(256) void transpose128(
    const float* __restrict__ src, float* __restrict__ dst, int R, int RP)
{
    __shared__ float tile[64][65];
    int r0 = blockIdx.x * 64;
    int c0 = blockIdx.y * 64;
    #pragma unroll
    for (int i = 0; i < 16; ++i) {
        int f = threadIdx.x + i * 256;
        int r = f >> 6, c = f & 63;
        int gr = r0 + r;
        tile[r][c] = (gr < R) ? src[(size_t)gr * DIM + (c0 + c)] : 0.f;
    }
    __syncthreads();
    #pragma unroll
    for (int i = 0; i < 16; ++i) {
        int f = threadIdx.x + i * 256;
        int c = f >> 6, r = f & 63;
        dst[(size_t)(c0 + c) * RP + (r0 + r)] = tile[r][c];
    }
}

// ---------------------------------------------------------------------------
// Kernel 2: logits[b][k] = sum_d x[b][d]*aw[k][d], via depth-major operands.
// 128x128 block tile, 8x8 micro-tile per thread (outer product over d).
// No LDS in hot loop: a-reads are 4-address broadcasts (L1), b-reads are
// coalesced 512B/wave streams (L1/L2). Epilogue is scalar stores because
// logits base (d_out+1) is only 4B-aligned.
__global__ __launch_bounds__(256) void gemm_kernel(
    const float* __restrict__ xT,    // [DIM][BATCH]
    const float* __restrict__ awT,   // [DIM][KP]
    float* __restrict__ logits)      // [BATCH][KCLS], 4B-aligned base
{
    int tx = threadIdx.x & 15;
    int ty = threadIdx.x >> 4;
    int n0 = blockIdx.x * 128 + 8 * tx;  // class
    int m0 = blockIdx.y * 128 + 8 * ty;  // batch
    const float* ap = xT + m0;
    const float* bp = awT + n0;

    float acc[8][8];
    #pragma unroll
    for (int i = 0; i < 8; ++i)
        #pragma unroll
        for (int j = 0; j < 8; ++j) acc[i][j] = 0.f;

    #pragma unroll 4
    for (int d = 0; d < DIM; ++d) {
        float4 a0 = *(const float4*)(ap);
        float4 a1 = *(const float4*)(ap + 4);
        float4 b0 = *(const float4*)(bp);
        float4 b1 = *(const float4*)(bp + 4);
        float av[8] = {a0.x, a0.y, a0.z, a0.w, a1.x, a1.y, a1.z, a1.w};
        float bv[8] = {b0.x, b0.y, b0.z, b0.w, b1.x, b1.y, b1.z, b1.w};
        #pragma unroll
        for (int i = 0; i < 8; ++i)
            #pragma unroll
            for (int j = 0; j < 8; ++j)
                acc[i][j] = fmaf(av[i], bv[j], acc[i][j]);
        ap += BATCH;
        bp += KP;
    }

    #pragma unroll
    for (int i = 0; i < 8; ++i) {
        float* crow = logits + (size_t)(m0 + i) * KCLS + n0;
        #pragma unroll
        for (int j = 0; j < 8; ++j) {
            if (n0 + j < KCLS) crow[j] = acc[i][j];
        }
    }
}

// ---------------------------------------------------------------------------
// Kernel 3: per-row logsumexp (one-pass online), then loss contribution.
__global__ __launch_bounds__(256) void lse_kernel(
    const float* __restrict__ logits, const int* __restrict__ y,
    float* __restrict__ loss)
{
    int b = blockIdx.x;
    const float* row = logits + (size_t)b * KCLS;
    float m = -INFINITY, s = 0.f;
    for (int k = threadIdx.x; k < KCLS; k += 256) {
        float v = row[k];
        if (v <= m) {
            s += __expf(v - m);
        } else {
            s = s * __expf(m - v) + 1.f;
            m = v;
        }
    }
    // wave (64-lane) reduction
    #pragma unroll
    for (int off = 32; off > 0; off >>= 1) {
        float m2 = __shfl_down(m, off);
        float s2 = __shfl_down(s, off);
        float M = fmaxf(m, m2);
        s = s * __expf(m - M) + s2 * __expf(m2 - M);
        m = M;
    }
    __shared__ float sm[4], ss[4];
    int w = threadIdx.x >> 6, l = threadIdx.x & 63;
    if (l == 0) { sm[w] = m; ss[w] = s; }
    __syncthreads();
    if (threadIdx.x == 0) {
        m = sm[0]; s = ss[0];
        #pragma unroll
        for (int i = 1; i < 4; ++i) {
            float M = fmaxf(m, sm[i]);
            s = s * __expf(m - M) + ss[i] * __expf(sm[i] - M);
            m = M;
        }
        float lse = m + __logf(s);
        float ly = row[y[b]];
        atomicAdd(loss, (lse - ly) * (1.0f / BATCH));
    }
}

// ---------------------------------------------------------------------------
extern "C" void kernel_launch(void* const* d_in, const int* in_sizes, int n_in,
                              void* d_out, int out_size, void* d_ws, size_t ws_size,
                              hipStream_t stream)
{
    const float* weights  = (const float*)d_in[0];   // [65536][128]
    const float* x        = (const float*)d_in[1];   // [1024][128]
    const int*   y        = (const int*)d_in[2];     // [1024]
    const int*   path_idx = (const int*)d_in[3];     // [50000][16]
    const int*   path_len = (const int*)d_in[4];     // [50000]

    float* out    = (float*)d_out;
    float* loss   = out;                                  // [1]
    float* logits = out + 1;                              // [1024][50000]
    float* aw     = out + 1 + (size_t)BATCH * KCLS;       // [50000][128]

    float* ws  = (float*)d_ws;
    float* awT = ws;                                      // [128][KP]
    float* xT  = ws + (size_t)DIM * KP;                   // [128][1024]

    hipMemsetAsync(loss, 0, sizeof(float), stream);

    aw_kernel<<<KCLS, 128, 0, stream>>>(weights, path_idx, path_len, aw);

    transpose128<<<dim3((KCLS + 63) / 64, 2), 256, 0, stream>>>(aw, awT, KCLS, KP);
    transpose128<<<dim3(BATCH / 64, 2), 256, 0, stream>>>(x, xT, BATCH, BATCH);

    gemm_kernel<<<dim3(KP / 128, BATCH / 128), 256, 0, stream>>>(xT, awT, logits);

    lse_kernel<<<BATCH, 256, 0, stream>>>(logits, y, loss);
}

// Round 2
// 388.851 us; speedup vs baseline: 2.0668x; 2.0668x over previous
//
#include <hip/hip_runtime.h>
#include <math.h>

#define KCLS  50000
#define KP    50048   // KCLS padded to multiple of 128 for the GEMM class dim
#define DIM   128
#define BATCH 1024
#define MAXD  16

typedef __attribute__((ext_vector_type(8))) short short8;
typedef __attribute__((ext_vector_type(4))) float floatx4;

// round-to-nearest-even float -> bf16 bits (inputs are finite)
__device__ __forceinline__ unsigned short f2bf(float f) {
    unsigned u = __float_as_uint(f);
    u += 0x7fffu + ((u >> 16) & 1u);
    return (unsigned short)(u >> 16);
}

// ---------------------------------------------------------------------------
// Kernel 1: added_weights[k] = weights[k] + sum_{p<len} weights[path_idx[k,p]]
// 8 classes per 256-thread block; 32 lanes x float4 per class row.
// Also emits the bf16 copy (padded to KP rows, pad rows zeroed) for the MFMA GEMM.
__global__ __launch_bounds__(256) void aw_kernel(
    const float* __restrict__ weights, const int* __restrict__ path_idx,
    const int* __restrict__ path_len, float* __restrict__ aw,
    unsigned short* __restrict__ awb)
{
    int t = threadIdx.x;
    int c = t >> 5;            // 0..7 local class
    int lane = t & 31;
    int k = blockIdx.x * 8 + c;
    int col = lane * 4;

    if (k >= KCLS) {           // zero-fill bf16 pad rows [KCLS, KP)
        ushort4 z = {0, 0, 0, 0};
        *(ushort4*)(awb + (size_t)k * DIM + col) = z;
        return;
    }

    float4 acc = *(const float4*)(weights + (size_t)k * DIM + col);
    int len = path_len[k];
    const int* pp = path_idx + (size_t)k * MAXD;
    for (int p = 0; p < len; ++p) {
        int idx = pp[p];
        float4 wv = *(const float4*)(weights + (size_t)idx * DIM + col);
        acc.x += wv.x; acc.y += wv.y; acc.z += wv.z; acc.w += wv.w;
    }
    *(float4*)(aw + (size_t)k * DIM + col) = acc;
    ushort4 hv = { f2bf(acc.x), f2bf(acc.y), f2bf(acc.z), f2bf(acc.w) };
    *(ushort4*)(awb + (size_t)k * DIM + col) = hv;
}

// ---------------------------------------------------------------------------
// x fp32 -> bf16  (1024*128 = 131072 elements, 4 per thread)
__global__ __launch_bounds__(256) void xconv_kernel(
    const float* __restrict__ x, unsigned short* __restrict__ xb)
{
    int i = (blockIdx.x * 256 + threadIdx.x) * 4;
    float4 v = *(const float4*)(x + i);
    ushort4 hv = { f2bf(v.x), f2bf(v.y), f2bf(v.z), f2bf(v.w) };
    *(ushort4*)(xb + i) = hv;
}

// ---------------------------------------------------------------------------
// Kernel 2: logits = Xb · Wb^T via bf16 MFMA 16x16x32.
// 128x128 block tile, 4 waves in 2x2, each wave 64x64 = 4x4 16x16 tiles.
// A-frag: lane r=lane&15 -> row, quad=lane>>4 -> k-octet; both operands are
// row-major [.][128] so every fragment is one contiguous 16B load (no LDS,
// no transpose). K=128 = 4 k-steps, fully unrolled.
__global__ __launch_bounds__(256) void gemm_kernel(
    const unsigned short* __restrict__ Xb,   // [BATCH][DIM] bf16
    const unsigned short* __restrict__ Wb,   // [KP][DIM] bf16
    float* __restrict__ logits)              // [BATCH][KCLS]
{
    int tid = threadIdx.x;
    int wave = tid >> 6, lane = tid & 63;
    int r = lane & 15, quad = lane >> 4;
    int m0 = blockIdx.y * 128 + (wave >> 1) * 64;
    int n0 = blockIdx.x * 128 + (wave & 1) * 64;

    const unsigned short* ap = Xb + (size_t)(m0 + r) * DIM + quad * 8;
    const unsigned short* bp = Wb + (size_t)(n0 + r) * DIM + quad * 8;

    floatx4 acc[4][4];
    #pragma unroll
    for (int i = 0; i < 4; ++i)
        #pragma unroll
        for (int j = 0; j < 4; ++j)
            acc[i][j] = (floatx4){0.f, 0.f, 0.f, 0.f};

    #pragma unroll
    for (int kk = 0; kk < 4; ++kk) {
        short8 a[4], b[4];
        #pragma unroll
        for (int i = 0; i < 4; ++i)
            a[i] = *(const short8*)(ap + (size_t)(i * 16) * DIM + kk * 32);
        #pragma unroll
        for (int j = 0; j < 4; ++j)
            b[j] = *(const short8*)(bp + (size_t)(j * 16) * DIM + kk * 32);
        #pragma unroll
        for (int i = 0; i < 4; ++i)
            #pragma unroll
            for (int j = 0; j < 4; ++j)
                acc[i][j] = __builtin_amdgcn_mfma_f32_16x16x32_bf16(
                    a[i], b[j], acc[i][j], 0, 0, 0);
    }

    #pragma unroll
    for (int i = 0; i < 4; ++i) {
        int mrow = m0 + i * 16 + quad * 4;
        #pragma unroll
        for (int j = 0; j < 4; ++j) {
            int col = n0 + j * 16 + r;
            if (col < KCLS) {
                float* cp = logits + (size_t)mrow * KCLS + col;
                #pragma unroll
                for (int reg = 0; reg < 4; ++reg)
                    cp[(size_t)reg * KCLS] = acc[i][j][reg];
            }
        }
    }
}

// ---------------------------------------------------------------------------
// Kernel 3: per-row logsumexp (online), float4 body (base is odd-float-aligned:
// 3-element head + 12499 float4 + 1-element tail = 50000), then loss.
__global__ __launch_bounds__(256) void lse_kernel(
    const float* __restrict__ logits, const int* __restrict__ y,
    float* __restrict__ loss)
{
    int b = blockIdx.x;
    const float* row = logits + (size_t)b * KCLS;
    float m = -INFINITY, s = 0.f;

    auto upd = [&](float v) {
        if (v <= m) {
            s += __expf(v - m);
        } else {
            s = s * __expf(m - v) + 1.f;
            m = v;
        }
    };

    if (threadIdx.x < 3) upd(row[threadIdx.x]);
    const float4* rv = (const float4*)(row + 3);
    for (int i = threadIdx.x; i < 12499; i += 256) {
        float4 v = rv[i];
        upd(v.x); upd(v.y); upd(v.z); upd(v.w);
    }
    if (threadIdx.x == 3) upd(row[49999]);

    #pragma unroll
    for (int off = 32; off > 0; off >>= 1) {
        float m2 = __shfl_down(m, off);
        float s2 = __shfl_down(s, off);
        float M = fmaxf(m, m2);
        s = s * __expf(m - M) + s2 * __expf(m2 - M);
        m = M;
    }
    __shared__ float sm[4], ss[4];
    int w = threadIdx.x >> 6, l = threadIdx.x & 63;
    if (l == 0) { sm[w] = m; ss[w] = s; }
    __syncthreads();
    if (threadIdx.x == 0) {
        m = sm[0]; s = ss[0];
        #pragma unroll
        for (int i = 1; i < 4; ++i) {
            float M = fmaxf(m, sm[i]);
            s = s * __expf(m - M) + ss[i] * __expf(sm[i] - M);
            m = M;
        }
        float lse = m + __logf(s);
        float ly = row[y[b]];
        atomicAdd(loss, (lse - ly) * (1.0f / BATCH));
    }
}

// ---------------------------------------------------------------------------
extern "C" void kernel_launch(void* const* d_in, const int* in_sizes, int n_in,
                              void* d_out, int out_size, void* d_ws, size_t ws_size,
                              hipStream_t stream)
{
    const float* weights  = (const float*)d_in[0];   // [65536][128]
    const float* x        = (const float*)d_in[1];   // [1024][128]
    const int*   y        = (const int*)d_in[2];     // [1024]
    const int*   path_idx = (const int*)d_in[3];     // [50000][16]
    const int*   path_len = (const int*)d_in[4];     // [50000]

    float* out    = (float*)d_out;
    float* loss   = out;                                  // [1]
    float* logits = out + 1;                              // [1024][50000]
    float* aw     = out + 1 + (size_t)BATCH * KCLS;       // [50000][128]

    unsigned short* awb = (unsigned short*)d_ws;          // [KP][128] bf16
    unsigned short* xb  = awb + (size_t)KP * DIM;         // [1024][128] bf16

    hipMemsetAsync(loss, 0, sizeof(float), stream);

    aw_kernel<<<KP / 8, 256, 0, stream>>>(weights, path_idx, path_len, aw, awb);
    xconv_kernel<<<BATCH * DIM / 1024, 256, 0, stream>>>(x, xb);

    gemm_kernel<<<dim3(KP / 128, BATCH / 128), 256, 0, stream>>>(xb, awb, logits);

    lse_kernel<<<BATCH, 256, 0, stream>>>(logits, y, loss);
}